// Round 1
// baseline (219.755 us; speedup 1.0000x reference)
//
#include <hip/hip_runtime.h>
#include <math.h>

// VQ-VAE vector quantizer for MI355X (gfx950).
// z: [32768, 64] fp32, codebook: [1024, 64] fp32.
// Outputs (flat float32, concatenated): quantized_st [32768*64], vq_loss [1],
// indices [32768] (as float), perplexity [1].
//
// R11: counters show total = ~44us harness ws-poison fill (visible as 256MiB
// fillBufferAligned dispatches) + vq_main ~38us + small kernels. vq_main is
// latency-bound: 2 waves/SIMD, 32 barrier phases at ~2850cy each vs ~700cy
// critical path. R11: (1) ROWS 64->32, grid 1024, waves split by code parity
// (wave (g,h) = row-group g, tiles h,h+2,..), __launch_bounds__(256,3) ->
// 3 blocks/CU; (2) B double-buffered tile PAIRS -> 16 barrier phases;
// (3) MFMA acc chains split 6->3 deep; (4) vq_final fused via last-block-done,
// lhist dropped (direct global atomics, only 32 updates/block).
// Numerics: 3-term split-bf16 + exact fp32 recheck (margin 1e-5), unchanged.

#define D 64
#define KC 1024
#define ROWS 32             // rows per block (2 row-groups x 16)
#define TC 32               // codes per LDS tile
#define NP (KC / (2 * TC))  // 16 pair-iterations
#define BCH 33              // chunk stride (16B chunks) for bank-conflict-free B
#define TILE_SH (16 * BCH * 8)  // 4224 shorts per tile slot

typedef short short8 __attribute__((ext_vector_type(8)));
typedef short short4v __attribute__((ext_vector_type(4)));
typedef float f32x4 __attribute__((ext_vector_type(4)));

__device__ __forceinline__ unsigned short f2bf(float x) {
  unsigned int u = __float_as_uint(x);
  unsigned int r = (u + 0x7fffu + ((u >> 16) & 1u)) >> 16;
  return (unsigned short)r;
}
__device__ __forceinline__ float bf2f(unsigned short h) {
  return __uint_as_float((unsigned int)h << 16);
}

// Precompute: exact fp32 code norms, split-bf16 codebook
// bsplit[k][128] = [e_hi(64) | e_lo(64)], zero hist/loss/done.
__global__ __launch_bounds__(256) void vq_prep(
    const float* __restrict__ cb, unsigned short* __restrict__ bsplit,
    float* __restrict__ cbn, unsigned int* __restrict__ hist,
    float* __restrict__ loss_acc, unsigned int* __restrict__ done) {
  const int k = blockIdx.x * 256 + threadIdx.x;  // 0..1023
  const float4* e = (const float4*)(cb + (size_t)k * D);
  unsigned short* bp = bsplit + (size_t)k * 128;
  float s0 = 0.f, s1 = 0.f, s2 = 0.f, s3 = 0.f;
#pragma unroll
  for (int i = 0; i < 16; ++i) {
    float4 v = e[i];
    s0 = fmaf(v.x, v.x, s0);
    s1 = fmaf(v.y, v.y, s1);
    s2 = fmaf(v.z, v.z, s2);
    s3 = fmaf(v.w, v.w, s3);
    unsigned short h0 = f2bf(v.x), h1 = f2bf(v.y), h2 = f2bf(v.z), h3 = f2bf(v.w);
    short4v hv = {(short)h0, (short)h1, (short)h2, (short)h3};
    short4v lv = {(short)f2bf(v.x - bf2f(h0)), (short)f2bf(v.y - bf2f(h1)),
                  (short)f2bf(v.z - bf2f(h2)), (short)f2bf(v.w - bf2f(h3))};
    *(short4v*)(bp + i * 4) = hv;
    *(short4v*)(bp + 64 + i * 4) = lv;
  }
  cbn[k] = (s0 + s1) + (s2 + s3);
  hist[k] = 0u;
  if (k == 0) {
    loss_acc[0] = 0.f;
    done[0] = 0u;
  }
}

__global__ __launch_bounds__(256, 3) void vq_main(
    const float* __restrict__ z, const unsigned short* __restrict__ bsplit,
    const float* __restrict__ cbn, const float* __restrict__ cb,
    float* __restrict__ out_q, float* __restrict__ out_idx,
    unsigned int* __restrict__ hist, float* __restrict__ loss_acc,
    unsigned int* __restrict__ done, float* __restrict__ out_loss,
    float* __restrict__ out_perp, float inv_n, float inv_nd) {
  // A' split-bf16 z tile: [32 rows][128 inner], stride 136 (bank-skew).
  __shared__ __align__(16) unsigned short Ash[ROWS * 136];
  // B double buffer of tile PAIRS: [buf][tile-in-pair][16 chunk-rows x 33].
  __shared__ __align__(16) unsigned short Bsh[2][2][TILE_SH];
  __shared__ float scbn[KC];
  __shared__ float srzp[ROWS * 16];
  __shared__ float srz[ROWS];
  __shared__ int skf[ROWS];
  __shared__ float swav[4];
  __shared__ float md1[ROWS], md2[ROWS];
  __shared__ int mkk1[ROWS], mkk2[ROWS];
  __shared__ float fpart[4];
  __shared__ int lastFlag;

  const int tid = threadIdx.x;
  const int lane = tid & 63;
  const int wav = tid >> 6;
  const int g = wav >> 1;  // row-group 0..1
  const int h = wav & 1;   // tile parity 0..1
  const int quad = lane >> 4;
  const int col = lane & 15;
  const int rowbase = blockIdx.x * ROWS;

  // ---- prologue: z tile -> Ash (split bf16) + row norms + cbn -> LDS +
  //      stage B pair 0
  const float4* z4 = (const float4*)(z + (size_t)rowbase * D);
#pragma unroll
  for (int it = 0; it < 2; ++it) {
    int f4 = it * 256 + tid;  // row*16 + (c4/4), 0..511
    int row = f4 >> 4, c4 = (f4 & 15) * 4;
    float4 v = z4[f4];
    srzp[f4] = ((v.x * v.x + v.y * v.y) + (v.z * v.z + v.w * v.w));
    unsigned short h0 = f2bf(v.x), h1 = f2bf(v.y), h2 = f2bf(v.z), h3 = f2bf(v.w);
    short4v hv = {(short)h0, (short)h1, (short)h2, (short)h3};
    short4v lv = {(short)f2bf(v.x - bf2f(h0)), (short)f2bf(v.y - bf2f(h1)),
                  (short)f2bf(v.z - bf2f(h2)), (short)f2bf(v.w - bf2f(h3))};
    *(short4v*)&Ash[row * 136 + c4] = hv;
    *(short4v*)&Ash[row * 136 + 64 + c4] = lv;
  }
  *(float4*)&scbn[tid * 4] = *(const float4*)&cbn[tid * 4];

  // stage pair 0: per tile, thread t moves global chunks t and t+256.
  // chunk g: code k=g>>4, plane-chunk jj=g&15; LDS slot = jj*BCH + k.
  const int cslot = (tid & 15) * BCH + (tid >> 4);
#pragma unroll
  for (int T = 0; T < 2; ++T) {
    const size_t off =
        (size_t)(T * TC + (tid >> 4)) * 128 + (size_t)(tid & 15) * 8;
    short8 s0 = *(const short8*)(bsplit + off);
    short8 s1 = *(const short8*)(bsplit + off + 2048);  // +16 codes
    *(short8*)&Bsh[0][T][cslot * 8] = s0;
    *(short8*)&Bsh[0][T][(cslot + 16) * 8] = s1;
  }
  __syncthreads();
  if (tid < ROWS) {
    float s = 0.f;
#pragma unroll
    for (int i = 0; i < 16; ++i) s += srzp[tid * 16 + i];
    srz[tid] = s;
  }
  __syncthreads();

  // wave (g,h) owns rows g*16..g*16+15, tiles h,h+2,...
  // A-frags: lane holds A[m=col][k=quad*8+j]
  const unsigned short* abase = &Ash[(g * 16 + col) * 136 + quad * 8];
  const short8 a0 = *(const short8*)(abase + 0);   // z_hi k 0..31
  const short8 a1 = *(const short8*)(abase + 32);  // z_hi k 32..63
  const short8 a2 = *(const short8*)(abase + 64);  // z_lo k 0..31
  const short8 a3 = *(const short8*)(abase + 96);  // z_lo k 32..63

  float rzv[4];
#pragma unroll
  for (int reg = 0; reg < 4; ++reg) rzv[reg] = srz[g * 16 + quad * 4 + reg];

  // per-lane exact top-2 over this lane's code class (col mod 16), this
  // wave's parity half of the codebook
  float b1d[4], b2d[4];
  int b1k[4], b2k[4];
#pragma unroll
  for (int i = 0; i < 4; ++i) {
    b1d[i] = 3.4e38f;
    b2d[i] = 3.4e38f;
    b1k[i] = 0x7fffffff;
    b2k[i] = 0x7fffffff;
  }

  // ---- K-loop: 16 pair-iterations, double-buffered LDS pairs
  for (int p = 0; p < NP; ++p) {
    const int kb = (p * 2 + h) * TC;  // this wave's tile within the pair
    const unsigned short* bcur = &Bsh[p & 1][h][0];
    // stage next pair: global -> regs (lands during this pair's compute)
    short8 st00, st01, st10, st11;
    if (p + 1 < NP) {
      const size_t base = (size_t)((p + 1) * 2) * TC;
      const size_t o0 = (base + (tid >> 4)) * 128 + (size_t)(tid & 15) * 8;
      const size_t o1 = (base + TC + (tid >> 4)) * 128 + (size_t)(tid & 15) * 8;
      st00 = *(const short8*)(bsplit + o0);
      st01 = *(const short8*)(bsplit + o0 + 2048);
      st10 = *(const short8*)(bsplit + o1);
      st11 = *(const short8*)(bsplit + o1 + 2048);
    }
    const float enA = scbn[kb + col];
    const float enB = scbn[kb + 16 + col];
    // B-frags: chain A = code col, chain B = code col+16.
    // frag i lives at chunk-row i*4+quad, slot = row*BCH + code.
    const short8 bA0 = *(const short8*)(bcur + ((0 + quad) * BCH + col) * 8);
    const short8 bA1 = *(const short8*)(bcur + ((4 + quad) * BCH + col) * 8);
    const short8 bA2 = *(const short8*)(bcur + ((8 + quad) * BCH + col) * 8);
    const short8 bA3 = *(const short8*)(bcur + ((12 + quad) * BCH + col) * 8);
    const short8 bB0 = *(const short8*)(bcur + ((0 + quad) * BCH + col + 16) * 8);
    const short8 bB1 = *(const short8*)(bcur + ((4 + quad) * BCH + col + 16) * 8);
    const short8 bB2 = *(const short8*)(bcur + ((8 + quad) * BCH + col + 16) * 8);
    const short8 bB3 = *(const short8*)(bcur + ((12 + quad) * BCH + col + 16) * 8);

    // 3-term split: hi.hi + lo.hi + hi.lo ; 4 independent chains (depth 3)
    f32x4 accA0 = {0.f, 0.f, 0.f, 0.f}, accA1 = {0.f, 0.f, 0.f, 0.f};
    f32x4 accB0 = {0.f, 0.f, 0.f, 0.f}, accB1 = {0.f, 0.f, 0.f, 0.f};
    accA0 = __builtin_amdgcn_mfma_f32_16x16x32_bf16(a0, bA0, accA0, 0, 0, 0);
    accB0 = __builtin_amdgcn_mfma_f32_16x16x32_bf16(a0, bB0, accB0, 0, 0, 0);
    accA1 = __builtin_amdgcn_mfma_f32_16x16x32_bf16(a1, bA1, accA1, 0, 0, 0);
    accB1 = __builtin_amdgcn_mfma_f32_16x16x32_bf16(a1, bB1, accB1, 0, 0, 0);
    accA0 = __builtin_amdgcn_mfma_f32_16x16x32_bf16(a2, bA0, accA0, 0, 0, 0);
    accB0 = __builtin_amdgcn_mfma_f32_16x16x32_bf16(a2, bB0, accB0, 0, 0, 0);
    accA1 = __builtin_amdgcn_mfma_f32_16x16x32_bf16(a3, bA1, accA1, 0, 0, 0);
    accB1 = __builtin_amdgcn_mfma_f32_16x16x32_bf16(a3, bB1, accB1, 0, 0, 0);
    accA0 = __builtin_amdgcn_mfma_f32_16x16x32_bf16(a0, bA2, accA0, 0, 0, 0);
    accB0 = __builtin_amdgcn_mfma_f32_16x16x32_bf16(a0, bB2, accB0, 0, 0, 0);
    accA1 = __builtin_amdgcn_mfma_f32_16x16x32_bf16(a1, bA3, accA1, 0, 0, 0);
    accB1 = __builtin_amdgcn_mfma_f32_16x16x32_bf16(a1, bB3, accB1, 0, 0, 0);

    // fold with exact per-lane top-2; strict < + ascending scan keeps lowest k
#pragma unroll
    for (int reg = 0; reg < 4; ++reg) {
      {
        float d = fmaf(-2.0f, accA0[reg] + accA1[reg], rzv[reg] + enA);
        int k = kb + col;
        bool w1 = d < b1d[reg];
        bool w2 = d < b2d[reg];
        b2d[reg] = w1 ? b1d[reg] : (w2 ? d : b2d[reg]);
        b2k[reg] = w1 ? b1k[reg] : (w2 ? k : b2k[reg]);
        b1d[reg] = w1 ? d : b1d[reg];
        b1k[reg] = w1 ? k : b1k[reg];
      }
      {
        float d = fmaf(-2.0f, accB0[reg] + accB1[reg], rzv[reg] + enB);
        int k = kb + 16 + col;
        bool w1 = d < b1d[reg];
        bool w2 = d < b2d[reg];
        b2d[reg] = w1 ? b1d[reg] : (w2 ? d : b2d[reg]);
        b2k[reg] = w1 ? b1k[reg] : (w2 ? k : b2k[reg]);
        b1d[reg] = w1 ? d : b1d[reg];
        b1k[reg] = w1 ? k : b1k[reg];
      }
    }

    // commit staged regs to the other pair buffer, then barrier
    if (p + 1 < NP) {
      unsigned short* bn0 = &Bsh[(p + 1) & 1][0][0];
      unsigned short* bn1 = &Bsh[(p + 1) & 1][1][0];
      *(short8*)&bn0[cslot * 8] = st00;
      *(short8*)&bn0[(cslot + 16) * 8] = st01;
      *(short8*)&bn1[cslot * 8] = st10;
      *(short8*)&bn1[(cslot + 16) * 8] = st11;
    }
    __syncthreads();
  }

  // ---- cross-lane top-2 butterfly over the 16 col-classes (within quad group)
#pragma unroll
  for (int m = 1; m < 16; m <<= 1) {
#pragma unroll
    for (int reg = 0; reg < 4; ++reg) {
      float od1 = __shfl_xor(b1d[reg], m, 64);
      int ok1 = __shfl_xor(b1k[reg], m, 64);
      float od2 = __shfl_xor(b2d[reg], m, 64);
      int ok2 = __shfl_xor(b2k[reg], m, 64);
      bool fo = (od1 < b1d[reg]) || (od1 == b1d[reg] && ok1 < b1k[reg]);
      float w1 = fo ? od1 : b1d[reg];
      int wk1 = fo ? ok1 : b1k[reg];
      float l1 = fo ? b1d[reg] : od1;
      int lk1 = fo ? b1k[reg] : ok1;
      bool so = (od2 < b2d[reg]) || (od2 == b2d[reg] && ok2 < b2k[reg]);
      float m2 = so ? od2 : b2d[reg];
      int mk2 = so ? ok2 : b2k[reg];
      bool lw = (l1 < m2) || (l1 == m2 && lk1 < mk2);
      b1d[reg] = w1;
      b1k[reg] = wk1;
      b2d[reg] = lw ? l1 : m2;
      b2k[reg] = lw ? lk1 : mk2;
    }
  }

  // ---- cross-parity merge: h==1 writers publish, h==0 writers merge+finish
  if (h == 1 && col < 4) {
    const int row = g * 16 + quad * 4 + col;
    md1[row] = b1d[col];
    mkk1[row] = b1k[col];
    md2[row] = b2d[col];
    mkk2[row] = b2k[col];
  }
  __syncthreads();

  if (h == 0 && col < 4) {
    const int row = g * 16 + quad * 4 + col;
    float bd1 = b1d[col], bd2 = b2d[col];
    int bk1 = b1k[col], bk2 = b2k[col];
    {
      float od1 = md1[row];
      int ok1 = mkk1[row];
      float od2 = md2[row];
      int ok2 = mkk2[row];
      bool fo = (od1 < bd1) || (od1 == bd1 && ok1 < bk1);
      float w1 = fo ? od1 : bd1;
      int wk1 = fo ? ok1 : bk1;
      float l1 = fo ? bd1 : od1;
      int lk1 = fo ? bk1 : ok1;
      bool so = (od2 < bd2) || (od2 == bd2 && ok2 < bk2);
      float m2 = so ? od2 : bd2;
      int mk2v = so ? ok2 : bk2;
      bool lw = (l1 < m2) || (l1 == m2 && lk1 < mk2v);
      bd1 = w1;
      bk1 = wk1;
      bd2 = lw ? l1 : m2;
      bk2 = lw ? lk1 : mk2v;
    }
    if (bd2 - bd1 < 1e-5f) {
      // exact fp32 recompute of the top-2 candidates
      const int grow = rowbase + row;
      const float4* zp = (const float4*)(z + (size_t)grow * D);
      float s0 = 0.f, s1 = 0.f, s2 = 0.f, s3 = 0.f;
#pragma unroll
      for (int i = 0; i < 16; ++i) {
        float4 v = zp[i];
        s0 = fmaf(v.x, v.x, s0);
        s1 = fmaf(v.y, v.y, s1);
        s2 = fmaf(v.z, v.z, s2);
        s3 = fmaf(v.w, v.w, s3);
      }
      const float rzx = (s0 + s1) + (s2 + s3);
      float dx[2];
      int kk[2] = {bk1, bk2};
#pragma unroll
      for (int c = 0; c < 2; ++c) {
        const float4* e4 = (const float4*)(cb + (size_t)kk[c] * D);
        float d0 = 0.f, d1 = 0.f, d2 = 0.f, d3 = 0.f;
#pragma unroll
        for (int i = 0; i < 16; ++i) {
          float4 v = e4[i];
          float4 zv = zp[i];
          d0 = fmaf(zv.x, v.x, d0);
          d1 = fmaf(zv.y, v.y, d1);
          d2 = fmaf(zv.z, v.z, d2);
          d3 = fmaf(zv.w, v.w, d3);
        }
        float dot = (d0 + d1) + (d2 + d3);
        dx[c] = (rzx + scbn[kk[c]]) - 2.0f * dot;
      }
      if ((dx[1] < dx[0]) || (dx[1] == dx[0] && bk2 < bk1)) bk1 = bk2;
    }
    skf[row] = bk1;
    out_idx[rowbase + row] = (float)bk1;
    atomicAdd(&hist[bk1], 1u);  // only 32 updates/block: direct global
  }
  __syncthreads();

  // ---- epilogue: quantized write (exact fp32 codebook rows) + loss partial
  float lsum = 0.f;
#pragma unroll
  for (int it = 0; it < 2; ++it) {
    int f4 = it * 256 + tid;
    int r = f4 >> 4;
    int c4 = (f4 & 15) * 4;
    int bk = skf[r];
    const float4 q = *(const float4*)(cb + (size_t)bk * D + c4);
    const int grow = rowbase + r;
    const float4 zv = *(const float4*)(z + (size_t)grow * D + c4);
    *(float4*)(out_q + (size_t)grow * D + c4) = q;
    float ax = q.x - zv.x, ay = q.y - zv.y, az = q.z - zv.z, aw = q.w - zv.w;
    lsum += ax * ax + ay * ay + az * az + aw * aw;
  }
#pragma unroll
  for (int off = 32; off > 0; off >>= 1) lsum += __shfl_down(lsum, off, 64);
  if (lane == 0) swav[wav] = lsum;
  __syncthreads();
  if (tid == 0) {
    atomicAdd(loss_acc, (swav[0] + swav[1]) + (swav[2] + swav[3]));
    __threadfence();
    unsigned int t = atomicAdd(done, 1u);
    lastFlag = (t == gridDim.x - 1) ? 1 : 0;
  }
  __syncthreads();

  // ---- fused finalize: last block computes perplexity + loss
  if (lastFlag) {
    __threadfence();
    float v = 0.f;
#pragma unroll
    for (int j = 0; j < KC / 256; ++j) {
      unsigned int c = atomicAdd(&hist[tid + 256 * j], 0u);  // coherent read
      float pr = (float)c * inv_n;
      v += pr * logf(pr + 1e-10f);
    }
#pragma unroll
    for (int off = 32; off > 0; off >>= 1) v += __shfl_down(v, off, 64);
    if (lane == 0) fpart[wav] = v;
    __syncthreads();
    if (tid == 0) {
      float la = atomicAdd(loss_acc, 0.0f);  // coherent read
      *out_perp = expf(-((fpart[0] + fpart[1]) + (fpart[2] + fpart[3])));
      // q_latent + 0.25*e_latent, both numerically mean((q-z)^2)
      *out_loss = 1.25f * la * inv_nd;
    }
  }
}

extern "C" void kernel_launch(void* const* d_in, const int* in_sizes, int n_in,
                              void* d_out, int out_size, void* d_ws,
                              size_t ws_size, hipStream_t stream) {
  (void)n_in;
  (void)out_size;
  (void)ws_size;
  const float* z = (const float*)d_in[0];
  const float* cb = (const float*)d_in[1];
  const int N = in_sizes[0] / D;  // 32768

  // Output layout (flat float32, reference return order):
  float* out_q = (float*)d_out;                     // N*D
  float* out_loss = (float*)d_out + (size_t)N * D;  // 1
  float* out_idx = out_loss + 1;                    // N
  float* out_perp = out_idx + N;                    // 1

  // Workspace (floats): hist[1024] @0, loss_acc @1024, done @1025,
  // cbn[1024] @1040, bsplit (short[1024*128]) @ float-idx 2064.
  unsigned int* hist = (unsigned int*)d_ws;
  float* loss_acc = (float*)d_ws + 1024;
  unsigned int* done = (unsigned int*)d_ws + 1025;
  float* cbn = (float*)d_ws + 1040;
  unsigned short* bsplit = (unsigned short*)((float*)d_ws + 2064);

  vq_prep<<<dim3(KC / 256), dim3(256), 0, stream>>>(cb, bsplit, cbn, hist,
                                                    loss_acc, done);
  vq_main<<<dim3(N / ROWS), dim3(256), 0, stream>>>(
      z, bsplit, cbn, cb, out_q, out_idx, hist, loss_acc, done, out_loss,
      out_perp, 1.0f / (float)N, 1.0f / ((float)N * (float)D));
}

// Round 2
// 98.058 us; speedup vs baseline: 2.2411x; 2.2411x over previous
//
#include <hip/hip_runtime.h>
#include <math.h>

// VQ-VAE vector quantizer for MI355X (gfx950).
// z: [32768, 64] fp32, codebook: [1024, 64] fp32.
// Outputs (flat float32, concatenated): quantized_st [32768*64], vq_loss [1],
// indices [32768] (as float), perplexity [1].
//
// R12: R11's fused finalize put a device-scope __threadfence in every block
// -> buffer_wbl2+buffer_inv per block -> 145 KB dirty-L2 writeback each
// (WRITE_SIZE 148 MB vs 8 MB ideal) + L2 bsplit invalidation refetch storm
// (FETCH 80 MB) -> vq_main 171 us. R12 reverts to the verified R10 structure
// (ROWS=64, grid 512, bounds(256,2), lhist, separate vq_final, NO fences)
// and applies the single orthogonal lever: B double-buffered as tile PAIRS,
// halving barrier phases 32 -> 16. Inner body = R10's, run twice per phase
// (independent acc chains -> free 4-chain MFMA ILP). LDS 47->64 KB, still
// 2 blocks/CU, so phase count is the only changed variable.
// Numerics: 3-term split-bf16 + exact fp32 recheck (margin 1e-5), unchanged.

#define D 64
#define KC 1024
#define ROWS 64           // rows per block (4 waves x 16 rows)
#define TC 32             // codes per LDS tile
#define NT (KC / TC)      // 32 tiles
#define NP (NT / 2)       // 16 pair-phases
#define BCH 33            // chunk stride (16B chunks) for bank-conflict-free B
#define TILE_SH (16 * BCH * 8)  // 4224 shorts per tile slot

typedef short short8 __attribute__((ext_vector_type(8)));
typedef short short4v __attribute__((ext_vector_type(4)));
typedef float f32x4 __attribute__((ext_vector_type(4)));

__device__ __forceinline__ unsigned short f2bf(float x) {
  unsigned int u = __float_as_uint(x);
  unsigned int r = (u + 0x7fffu + ((u >> 16) & 1u)) >> 16;
  return (unsigned short)r;
}
__device__ __forceinline__ float bf2f(unsigned short h) {
  return __uint_as_float((unsigned int)h << 16);
}

// Precompute: exact fp32 code norms, split-bf16 codebook
// bsplit[k][128] = [e_hi(64) | e_lo(64)], zero hist/loss.
__global__ __launch_bounds__(256) void vq_prep(
    const float* __restrict__ cb, unsigned short* __restrict__ bsplit,
    float* __restrict__ cbn, unsigned int* __restrict__ hist,
    float* __restrict__ loss_acc) {
  const int k = blockIdx.x * 256 + threadIdx.x;  // 0..1023
  const float4* e = (const float4*)(cb + (size_t)k * D);
  unsigned short* bp = bsplit + (size_t)k * 128;
  float s0 = 0.f, s1 = 0.f, s2 = 0.f, s3 = 0.f;
#pragma unroll
  for (int i = 0; i < 16; ++i) {
    float4 v = e[i];
    s0 = fmaf(v.x, v.x, s0);
    s1 = fmaf(v.y, v.y, s1);
    s2 = fmaf(v.z, v.z, s2);
    s3 = fmaf(v.w, v.w, s3);
    unsigned short h0 = f2bf(v.x), h1 = f2bf(v.y), h2 = f2bf(v.z), h3 = f2bf(v.w);
    short4v hv = {(short)h0, (short)h1, (short)h2, (short)h3};
    short4v lv = {(short)f2bf(v.x - bf2f(h0)), (short)f2bf(v.y - bf2f(h1)),
                  (short)f2bf(v.z - bf2f(h2)), (short)f2bf(v.w - bf2f(h3))};
    *(short4v*)(bp + i * 4) = hv;
    *(short4v*)(bp + 64 + i * 4) = lv;
  }
  cbn[k] = (s0 + s1) + (s2 + s3);
  hist[k] = 0u;
  if (k == 0) loss_acc[0] = 0.f;
}

__global__ __launch_bounds__(256, 2) void vq_main(
    const float* __restrict__ z, const unsigned short* __restrict__ bsplit,
    const float* __restrict__ cbn, const float* __restrict__ cb,
    float* __restrict__ out_q, float* __restrict__ out_idx,
    unsigned int* __restrict__ hist, float* __restrict__ loss_acc) {
  // A' split-bf16 z tile: [64 rows][128 inner], stride 136 (bank-skew).
  __shared__ __align__(16) unsigned short Ash[ROWS * 136];
  // B double buffer of tile PAIRS: [buf][tile-in-pair][16 chunk-rows x 33].
  __shared__ __align__(16) unsigned short Bsh[2][2][TILE_SH];
  __shared__ float scbn[KC];
  __shared__ float srzp[ROWS * 16];
  __shared__ float srz[ROWS];
  __shared__ int skf[ROWS];
  __shared__ float swav[4];
  __shared__ unsigned int lhist[KC];

  const int tid = threadIdx.x;
  const int lane = tid & 63;
  const int wav = tid >> 6;
  const int quad = lane >> 4;
  const int col = lane & 15;
  const int rowbase = blockIdx.x * ROWS;

  // ---- prologue: z tile -> Ash (split bf16) + row norms + cbn -> LDS +
  //      stage B pair 0 + zero lhist
  const float4* z4 = (const float4*)(z + (size_t)rowbase * D);
#pragma unroll
  for (int it = 0; it < 4; ++it) {
    int f4 = it * 256 + tid;  // row*16 + (c4/4)
    int row = f4 >> 4, c4 = (f4 & 15) * 4;
    float4 v = z4[f4];
    srzp[f4] = ((v.x * v.x + v.y * v.y) + (v.z * v.z + v.w * v.w));
    unsigned short h0 = f2bf(v.x), h1 = f2bf(v.y), h2 = f2bf(v.z), h3 = f2bf(v.w);
    short4v hv = {(short)h0, (short)h1, (short)h2, (short)h3};
    short4v lv = {(short)f2bf(v.x - bf2f(h0)), (short)f2bf(v.y - bf2f(h1)),
                  (short)f2bf(v.z - bf2f(h2)), (short)f2bf(v.w - bf2f(h3))};
    *(short4v*)&Ash[row * 136 + c4] = hv;
    *(short4v*)&Ash[row * 136 + 64 + c4] = lv;
  }
  *(float4*)&scbn[tid * 4] = *(const float4*)&cbn[tid * 4];
#pragma unroll
  for (int j = 0; j < KC / 256; ++j) lhist[tid + 256 * j] = 0u;

  // stage pair 0: per tile, thread t moves global chunks t and t+256.
  // chunk g: code k=g>>4, plane-chunk jj=g&15; LDS slot = jj*BCH + k.
  const int cslot = (tid & 15) * BCH + (tid >> 4);  // slot for chunk tid
#pragma unroll
  for (int T = 0; T < 2; ++T) {
    const size_t off =
        (size_t)(T * TC + (tid >> 4)) * 128 + (size_t)(tid & 15) * 8;
    short8 s0 = *(const short8*)(bsplit + off);
    short8 s1 = *(const short8*)(bsplit + off + 2048);  // +16 codes
    *(short8*)&Bsh[0][T][cslot * 8] = s0;
    *(short8*)&Bsh[0][T][(cslot + 16) * 8] = s1;
  }
  __syncthreads();
  if (tid < ROWS) {
    float s = 0.f;
#pragma unroll
    for (int i = 0; i < 16; ++i) s += srzp[tid * 16 + i];
    srz[tid] = s;
  }
  __syncthreads();

  // wave w owns block rows w*16..w*16+15. A-frags: lane holds A[m=col][k=quad*8+j]
  const unsigned short* abase = &Ash[(wav * 16 + col) * 136 + quad * 8];
  const short8 a0 = *(const short8*)(abase + 0);   // z_hi k 0..31
  const short8 a1 = *(const short8*)(abase + 32);  // z_hi k 32..63
  const short8 a2 = *(const short8*)(abase + 64);  // z_lo k 0..31
  const short8 a3 = *(const short8*)(abase + 96);  // z_lo k 32..63

  float rzv[4];
#pragma unroll
  for (int reg = 0; reg < 4; ++reg) rzv[reg] = srz[wav * 16 + quad * 4 + reg];

  // per-lane exact top-2 over this lane's code class (col mod 16)
  float b1d[4], b2d[4];
  int b1k[4], b2k[4];
#pragma unroll
  for (int i = 0; i < 4; ++i) {
    b1d[i] = 3.4e38f; b2d[i] = 3.4e38f;
    b1k[i] = 0x7fffffff; b2k[i] = 0x7fffffff;
  }

  // ---- K-loop: 16 pair-phases of 2x32 codes, double-buffered LDS pairs
  for (int p = 0; p < NP; ++p) {
    // stage next pair: global -> regs (lands during this phase's compute)
    short8 st00, st01, st10, st11;
    if (p + 1 < NP) {
      const size_t base = (size_t)((p + 1) * 2) * TC;
      const size_t o0 = (base + (tid >> 4)) * 128 + (size_t)(tid & 15) * 8;
      st00 = *(const short8*)(bsplit + o0);
      st01 = *(const short8*)(bsplit + o0 + 2048);
      st10 = *(const short8*)(bsplit + o0 + 4096);  // +32 codes (tile 1)
      st11 = *(const short8*)(bsplit + o0 + 6144);
    }
#pragma unroll
    for (int T = 0; T < 2; ++T) {
      const int kb = (p * 2 + T) * TC;
      const unsigned short* bcur = &Bsh[p & 1][T][0];
      const float enA = scbn[kb + col];
      const float enB = scbn[kb + 16 + col];
      // B-frags: chain A = code col, chain B = code col+16.
      // frag i lives at chunk-row i*4+quad, slot = row*BCH + code.
      const short8 bA0 = *(const short8*)(bcur + ((0 + quad) * BCH + col) * 8);
      const short8 bA1 = *(const short8*)(bcur + ((4 + quad) * BCH + col) * 8);
      const short8 bA2 = *(const short8*)(bcur + ((8 + quad) * BCH + col) * 8);
      const short8 bA3 = *(const short8*)(bcur + ((12 + quad) * BCH + col) * 8);
      const short8 bB0 =
          *(const short8*)(bcur + ((0 + quad) * BCH + col + 16) * 8);
      const short8 bB1 =
          *(const short8*)(bcur + ((4 + quad) * BCH + col + 16) * 8);
      const short8 bB2 =
          *(const short8*)(bcur + ((8 + quad) * BCH + col + 16) * 8);
      const short8 bB3 =
          *(const short8*)(bcur + ((12 + quad) * BCH + col + 16) * 8);

      f32x4 accA = {0.f, 0.f, 0.f, 0.f}, accB = {0.f, 0.f, 0.f, 0.f};
      // 3-term split: hi.hi + lo.hi + hi.lo ; two independent chains per tile
      accA = __builtin_amdgcn_mfma_f32_16x16x32_bf16(a0, bA0, accA, 0, 0, 0);
      accB = __builtin_amdgcn_mfma_f32_16x16x32_bf16(a0, bB0, accB, 0, 0, 0);
      accA = __builtin_amdgcn_mfma_f32_16x16x32_bf16(a1, bA1, accA, 0, 0, 0);
      accB = __builtin_amdgcn_mfma_f32_16x16x32_bf16(a1, bB1, accB, 0, 0, 0);
      accA = __builtin_amdgcn_mfma_f32_16x16x32_bf16(a2, bA0, accA, 0, 0, 0);
      accB = __builtin_amdgcn_mfma_f32_16x16x32_bf16(a2, bB0, accB, 0, 0, 0);
      accA = __builtin_amdgcn_mfma_f32_16x16x32_bf16(a3, bA1, accA, 0, 0, 0);
      accB = __builtin_amdgcn_mfma_f32_16x16x32_bf16(a3, bB1, accB, 0, 0, 0);
      accA = __builtin_amdgcn_mfma_f32_16x16x32_bf16(a0, bA2, accA, 0, 0, 0);
      accB = __builtin_amdgcn_mfma_f32_16x16x32_bf16(a0, bB2, accB, 0, 0, 0);
      accA = __builtin_amdgcn_mfma_f32_16x16x32_bf16(a1, bA3, accA, 0, 0, 0);
      accB = __builtin_amdgcn_mfma_f32_16x16x32_bf16(a1, bB3, accB, 0, 0, 0);

      // fold with exact per-lane top-2; strict < + ascending scan keeps lowest k
#pragma unroll
      for (int reg = 0; reg < 4; ++reg) {
        {
          float d = fmaf(-2.0f, accA[reg], rzv[reg] + enA);
          int k = kb + col;
          bool w1 = d < b1d[reg];
          bool w2 = d < b2d[reg];
          b2d[reg] = w1 ? b1d[reg] : (w2 ? d : b2d[reg]);
          b2k[reg] = w1 ? b1k[reg] : (w2 ? k : b2k[reg]);
          b1d[reg] = w1 ? d : b1d[reg];
          b1k[reg] = w1 ? k : b1k[reg];
        }
        {
          float d = fmaf(-2.0f, accB[reg], rzv[reg] + enB);
          int k = kb + 16 + col;
          bool w1 = d < b1d[reg];
          bool w2 = d < b2d[reg];
          b2d[reg] = w1 ? b1d[reg] : (w2 ? d : b2d[reg]);
          b2k[reg] = w1 ? b1k[reg] : (w2 ? k : b2k[reg]);
          b1d[reg] = w1 ? d : b1d[reg];
          b1k[reg] = w1 ? k : b1k[reg];
        }
      }
    }

    // commit staged regs to the other pair buffer, then barrier
    if (p + 1 < NP) {
      unsigned short* bn0 = &Bsh[(p + 1) & 1][0][0];
      unsigned short* bn1 = &Bsh[(p + 1) & 1][1][0];
      *(short8*)&bn0[cslot * 8] = st00;
      *(short8*)&bn0[(cslot + 16) * 8] = st01;
      *(short8*)&bn1[cslot * 8] = st10;
      *(short8*)&bn1[(cslot + 16) * 8] = st11;
    }
    __syncthreads();
  }

  // ---- cross-lane top-2 butterfly over the 16 col-classes (within quad group)
#pragma unroll
  for (int m = 1; m < 16; m <<= 1) {
#pragma unroll
    for (int reg = 0; reg < 4; ++reg) {
      float od1 = __shfl_xor(b1d[reg], m, 64);
      int ok1 = __shfl_xor(b1k[reg], m, 64);
      float od2 = __shfl_xor(b2d[reg], m, 64);
      int ok2 = __shfl_xor(b2k[reg], m, 64);
      bool fo = (od1 < b1d[reg]) || (od1 == b1d[reg] && ok1 < b1k[reg]);
      float w1 = fo ? od1 : b1d[reg];
      int wk1 = fo ? ok1 : b1k[reg];
      float l1 = fo ? b1d[reg] : od1;
      int lk1 = fo ? b1k[reg] : ok1;
      bool so = (od2 < b2d[reg]) || (od2 == b2d[reg] && ok2 < b2k[reg]);
      float m2 = so ? od2 : b2d[reg];
      int mk2 = so ? ok2 : b2k[reg];
      bool lw = (l1 < m2) || (l1 == m2 && lk1 < mk2);
      b1d[reg] = w1;
      b1k[reg] = wk1;
      b2d[reg] = lw ? l1 : m2;
      b2k[reg] = lw ? lk1 : mk2;
    }
  }

  // writer lanes: col<4 handles row = wav*16 + quad*4 + col (using reg=col)
  if (col < 4) {
    const int row = wav * 16 + quad * 4 + col;
    float bd1 = b1d[col], bd2 = b2d[col];
    int bk1 = b1k[col], bk2 = b2k[col];
    if (bd2 - bd1 < 1e-5f) {
      // exact fp32 recompute (R3 arithmetic) of the top-2 candidates
      const int grow = rowbase + row;
      const float4* zp = (const float4*)(z + (size_t)grow * D);
      float s0 = 0.f, s1 = 0.f, s2 = 0.f, s3 = 0.f;
#pragma unroll
      for (int i = 0; i < 16; ++i) {
        float4 v = zp[i];
        s0 = fmaf(v.x, v.x, s0);
        s1 = fmaf(v.y, v.y, s1);
        s2 = fmaf(v.z, v.z, s2);
        s3 = fmaf(v.w, v.w, s3);
      }
      const float rzx = (s0 + s1) + (s2 + s3);
      float dx[2];
      int kk[2] = {bk1, bk2};
#pragma unroll
      for (int c = 0; c < 2; ++c) {
        const float4* e4 = (const float4*)(cb + (size_t)kk[c] * D);
        float d0 = 0.f, d1 = 0.f, d2 = 0.f, d3 = 0.f;
#pragma unroll
        for (int i = 0; i < 16; ++i) {
          float4 v = e4[i];
          float4 zv = zp[i];
          d0 = fmaf(zv.x, v.x, d0);
          d1 = fmaf(zv.y, v.y, d1);
          d2 = fmaf(zv.z, v.z, d2);
          d3 = fmaf(zv.w, v.w, d3);
        }
        float dot = (d0 + d1) + (d2 + d3);
        dx[c] = (rzx + scbn[kk[c]]) - 2.0f * dot;
      }
      if ((dx[1] < dx[0]) || (dx[1] == dx[0] && bk2 < bk1)) bk1 = bk2;
    }
    skf[row] = bk1;
    out_idx[rowbase + row] = (float)bk1;
    atomicAdd(&lhist[bk1], 1u);
  }
  __syncthreads();

  // ---- flush per-block histogram: one global atomic per distinct code
#pragma unroll
  for (int j = 0; j < KC / 256; ++j) {
    unsigned int c = lhist[tid + 256 * j];
    if (c) atomicAdd(&hist[tid + 256 * j], c);
  }

  // ---- epilogue: quantized write (exact fp32 codebook rows) + loss partial
  float lsum = 0.f;
#pragma unroll
  for (int it = 0; it < 4; ++it) {
    int f4 = it * 256 + tid;
    int r = f4 >> 4;
    int c4 = (f4 & 15) * 4;
    int bk = skf[r];
    const float4 q = *(const float4*)(cb + (size_t)bk * D + c4);
    const int grow = rowbase + r;
    const float4 zv = *(const float4*)(z + (size_t)grow * D + c4);
    *(float4*)(out_q + (size_t)grow * D + c4) = q;
    float ax = q.x - zv.x, ay = q.y - zv.y, az = q.z - zv.z, aw = q.w - zv.w;
    lsum += ax * ax + ay * ay + az * az + aw * aw;
  }
#pragma unroll
  for (int off = 32; off > 0; off >>= 1) lsum += __shfl_down(lsum, off, 64);
  if (lane == 0) swav[wav] = lsum;
  __syncthreads();
  if (tid == 0) {
    atomicAdd(loss_acc, (swav[0] + swav[1]) + (swav[2] + swav[3]));
  }
}

__global__ __launch_bounds__(1024) void vq_final(
    const unsigned int* __restrict__ hist, const float* __restrict__ loss_acc,
    float* __restrict__ out_loss, float* __restrict__ out_perp, float inv_n,
    float inv_nd) {
  __shared__ float part[16];
  const int t = threadIdx.x;
  const int lane = t & 63;
  const int wav = t >> 6;
  float p = (float)hist[t] * inv_n;
  float v = p * logf(p + 1e-10f);
#pragma unroll
  for (int off = 32; off > 0; off >>= 1) v += __shfl_down(v, off, 64);
  if (lane == 0) part[wav] = v;
  __syncthreads();
  if (t == 0) {
    float s = 0.f;
#pragma unroll
    for (int j = 0; j < 16; ++j) s += part[j];
    *out_perp = expf(-s);
    // q_latent + 0.25*e_latent, both numerically mean((q-z)^2)
    *out_loss = 1.25f * loss_acc[0] * inv_nd;
  }
}

extern "C" void kernel_launch(void* const* d_in, const int* in_sizes, int n_in,
                              void* d_out, int out_size, void* d_ws,
                              size_t ws_size, hipStream_t stream) {
  (void)n_in;
  (void)out_size;
  (void)ws_size;
  const float* z = (const float*)d_in[0];
  const float* cb = (const float*)d_in[1];
  const int N = in_sizes[0] / D;  // 32768

  // Output layout (flat float32, reference return order):
  float* out_q = (float*)d_out;                     // N*D
  float* out_loss = (float*)d_out + (size_t)N * D;  // 1
  float* out_idx = out_loss + 1;                    // N
  float* out_perp = out_idx + N;                    // 1

  // Workspace (floats): hist[1024] @0, loss_acc @1024, cbn[1024] @1040,
  // bsplit (short[1024*128]) @ float-idx 2064 (byte 8256, 16B-aligned).
  unsigned int* hist = (unsigned int*)d_ws;
  float* loss_acc = (float*)d_ws + 1024;
  float* cbn = (float*)d_ws + 1040;
  unsigned short* bsplit = (unsigned short*)((float*)d_ws + 2064);

  vq_prep<<<dim3(KC / 256), dim3(256), 0, stream>>>(cb, bsplit, cbn, hist,
                                                    loss_acc);
  vq_main<<<dim3(N / ROWS), dim3(256), 0, stream>>>(z, bsplit, cbn, cb, out_q,
                                                    out_idx, hist, loss_acc);
  vq_final<<<dim3(1), dim3(1024), 0, stream>>>(
      hist, loss_acc, out_loss, out_perp, 1.0f / (float)N,
      1.0f / ((float)N * (float)D));
}

// Round 3
// 97.609 us; speedup vs baseline: 2.2514x; 1.0046x over previous
//
#include <hip/hip_runtime.h>
#include <math.h>

// VQ-VAE vector quantizer for MI355X (gfx950).
// z: [32768, 64] fp32, codebook: [1024, 64] fp32.
// Outputs (flat float32, concatenated): quantized_st [32768*64], vq_loss [1],
// indices [32768] (as float), perplexity [1].
//
// R13: R12 (16 pair-phases) won ~4us but traded occupancy: LDS 47->64 KB
// dropped 3->2 blocks/CU. R13 keeps 16 phases AND restores 3 blocks/CU via
// an LDS diet: Ash/srzp/srz (21.7 KB) were only a transpose staging for the
// one-time A-fragment load -> replaced by direct per-lane global z loads
// (4 float4 per lane) + in-register split-bf16 + shfl row-norm reduction
// (norm cancels in all distance comparisons, so precision is irrelevant for
// selection; recheck recomputes it exactly). LDS 42.3 KB -> 3 blocks/CU,
// bounds(256,3), two prologue barriers removed.
// Numerics: 3-term split-bf16 + exact fp32 recheck (margin 1e-5), unchanged.

#define D 64
#define KC 1024
#define ROWS 64           // rows per block (4 waves x 16 rows)
#define TC 32             // codes per LDS tile
#define NT (KC / TC)      // 32 tiles
#define NP (NT / 2)       // 16 pair-phases
#define BCH 33            // chunk stride (16B chunks) for bank-conflict-free B
#define TILE_SH (16 * BCH * 8)  // 4224 shorts per tile slot

typedef short short8 __attribute__((ext_vector_type(8)));
typedef short short4v __attribute__((ext_vector_type(4)));
typedef float f32x4 __attribute__((ext_vector_type(4)));

__device__ __forceinline__ unsigned short f2bf(float x) {
  unsigned int u = __float_as_uint(x);
  unsigned int r = (u + 0x7fffu + ((u >> 16) & 1u)) >> 16;
  return (unsigned short)r;
}
__device__ __forceinline__ float bf2f(unsigned short h) {
  return __uint_as_float((unsigned int)h << 16);
}

// split two float4 (8 floats) into hi/lo bf16 short8
__device__ __forceinline__ void split8(const float4 a, const float4 b,
                                       short8* hi, short8* lo) {
  float f[8] = {a.x, a.y, a.z, a.w, b.x, b.y, b.z, b.w};
#pragma unroll
  for (int i = 0; i < 8; ++i) {
    unsigned short h = f2bf(f[i]);
    (*hi)[i] = (short)h;
    (*lo)[i] = (short)f2bf(f[i] - bf2f(h));
  }
}

// Precompute: exact fp32 code norms, split-bf16 codebook
// bsplit[k][128] = [e_hi(64) | e_lo(64)], zero hist/loss.
__global__ __launch_bounds__(256) void vq_prep(
    const float* __restrict__ cb, unsigned short* __restrict__ bsplit,
    float* __restrict__ cbn, unsigned int* __restrict__ hist,
    float* __restrict__ loss_acc) {
  const int k = blockIdx.x * 256 + threadIdx.x;  // 0..1023
  const float4* e = (const float4*)(cb + (size_t)k * D);
  unsigned short* bp = bsplit + (size_t)k * 128;
  float s0 = 0.f, s1 = 0.f, s2 = 0.f, s3 = 0.f;
#pragma unroll
  for (int i = 0; i < 16; ++i) {
    float4 v = e[i];
    s0 = fmaf(v.x, v.x, s0);
    s1 = fmaf(v.y, v.y, s1);
    s2 = fmaf(v.z, v.z, s2);
    s3 = fmaf(v.w, v.w, s3);
    unsigned short h0 = f2bf(v.x), h1 = f2bf(v.y), h2 = f2bf(v.z), h3 = f2bf(v.w);
    short4v hv = {(short)h0, (short)h1, (short)h2, (short)h3};
    short4v lv = {(short)f2bf(v.x - bf2f(h0)), (short)f2bf(v.y - bf2f(h1)),
                  (short)f2bf(v.z - bf2f(h2)), (short)f2bf(v.w - bf2f(h3))};
    *(short4v*)(bp + i * 4) = hv;
    *(short4v*)(bp + 64 + i * 4) = lv;
  }
  cbn[k] = (s0 + s1) + (s2 + s3);
  hist[k] = 0u;
  if (k == 0) loss_acc[0] = 0.f;
}

__global__ __launch_bounds__(256, 3) void vq_main(
    const float* __restrict__ z, const unsigned short* __restrict__ bsplit,
    const float* __restrict__ cbn, const float* __restrict__ cb,
    float* __restrict__ out_q, float* __restrict__ out_idx,
    unsigned int* __restrict__ hist, float* __restrict__ loss_acc) {
  // B double buffer of tile PAIRS: [buf][tile-in-pair][16 chunk-rows x 33].
  __shared__ __align__(16) unsigned short Bsh[2][2][TILE_SH];
  __shared__ float scbn[KC];
  __shared__ int skf[ROWS];
  __shared__ float swav[4];
  __shared__ unsigned int lhist[KC];

  const int tid = threadIdx.x;
  const int lane = tid & 63;
  const int wav = tid >> 6;
  const int quad = lane >> 4;
  const int col = lane & 15;
  const int rowbase = blockIdx.x * ROWS;

  // ---- prologue
  // Direct A-fragment z loads: lane owns row wav*16+col,
  // k in {quad*8..+8, 32+quad*8..+8} -> 4 float4 (issue first, longest dep).
  const int arow = rowbase + wav * 16 + col;
  const float4* zr = (const float4*)(z + (size_t)arow * D);
  const float4 f0 = zr[quad * 2];
  const float4 f1 = zr[quad * 2 + 1];
  const float4 f2 = zr[8 + quad * 2];
  const float4 f3 = zr[8 + quad * 2 + 1];

  // cbn -> LDS, zero lhist
  *(float4*)&scbn[tid * 4] = *(const float4*)&cbn[tid * 4];
#pragma unroll
  for (int j = 0; j < KC / 256; ++j) lhist[tid + 256 * j] = 0u;

  // stage pair 0: per tile, thread t moves global chunks t and t+256.
  // chunk g: code k=g>>4, plane-chunk jj=g&15; LDS slot = jj*BCH + k.
  const int cslot = (tid & 15) * BCH + (tid >> 4);  // slot for chunk tid
#pragma unroll
  for (int T = 0; T < 2; ++T) {
    const size_t off =
        (size_t)(T * TC + (tid >> 4)) * 128 + (size_t)(tid & 15) * 8;
    short8 s0 = *(const short8*)(bsplit + off);
    short8 s1 = *(const short8*)(bsplit + off + 2048);  // +16 codes
    *(short8*)&Bsh[0][T][cslot * 8] = s0;
    *(short8*)&Bsh[0][T][(cslot + 16) * 8] = s1;
  }

  // in-register split-bf16 A-frags
  short8 a0, a1, a2, a3;
  split8(f0, f1, &a0, &a2);  // z_hi / z_lo, k = quad*8 .. +8
  split8(f2, f3, &a1, &a3);  // z_hi / z_lo, k = 32+quad*8 .. +8

  // row norm: per-lane partial (16 elems), quads of same col cover the row.
  float nrm = ((f0.x * f0.x + f0.y * f0.y) + (f0.z * f0.z + f0.w * f0.w)) +
              ((f1.x * f1.x + f1.y * f1.y) + (f1.z * f1.z + f1.w * f1.w)) +
              ((f2.x * f2.x + f2.y * f2.y) + (f2.z * f2.z + f2.w * f2.w)) +
              ((f3.x * f3.x + f3.y * f3.y) + (f3.z * f3.z + f3.w * f3.w));
  nrm += __shfl_xor(nrm, 16, 64);
  nrm += __shfl_xor(nrm, 32, 64);
  // acc[reg] corresponds to output row quad*4+reg; its norm lives at lane
  // col'=quad*4+reg (any quad). Norm is row-constant so precision only
  // shifts all distances of a row equally -> selection unaffected.
  float rzv[4];
#pragma unroll
  for (int r = 0; r < 4; ++r) rzv[r] = __shfl(nrm, quad * 4 + r, 64);

  __syncthreads();  // covers pair-0 ds_writes + scbn + lhist

  // per-lane exact top-2 over this lane's code class (col mod 16)
  float b1d[4], b2d[4];
  int b1k[4], b2k[4];
#pragma unroll
  for (int i = 0; i < 4; ++i) {
    b1d[i] = 3.4e38f; b2d[i] = 3.4e38f;
    b1k[i] = 0x7fffffff; b2k[i] = 0x7fffffff;
  }

  // ---- K-loop: 16 pair-phases of 2x32 codes, double-buffered LDS pairs
  for (int p = 0; p < NP; ++p) {
    // stage next pair: global -> regs (lands during this phase's compute)
    short8 st00, st01, st10, st11;
    if (p + 1 < NP) {
      const size_t base = (size_t)((p + 1) * 2) * TC;
      const size_t o0 = (base + (tid >> 4)) * 128 + (size_t)(tid & 15) * 8;
      st00 = *(const short8*)(bsplit + o0);
      st01 = *(const short8*)(bsplit + o0 + 2048);
      st10 = *(const short8*)(bsplit + o0 + 4096);  // +32 codes (tile 1)
      st11 = *(const short8*)(bsplit + o0 + 6144);
    }
#pragma unroll
    for (int T = 0; T < 2; ++T) {
      const int kb = (p * 2 + T) * TC;
      const unsigned short* bcur = &Bsh[p & 1][T][0];
      const float enA = scbn[kb + col];
      const float enB = scbn[kb + 16 + col];
      // B-frags: chain A = code col, chain B = code col+16.
      // frag i lives at chunk-row i*4+quad, slot = row*BCH + code.
      const short8 bA0 = *(const short8*)(bcur + ((0 + quad) * BCH + col) * 8);
      const short8 bA1 = *(const short8*)(bcur + ((4 + quad) * BCH + col) * 8);
      const short8 bA2 = *(const short8*)(bcur + ((8 + quad) * BCH + col) * 8);
      const short8 bA3 = *(const short8*)(bcur + ((12 + quad) * BCH + col) * 8);
      const short8 bB0 =
          *(const short8*)(bcur + ((0 + quad) * BCH + col + 16) * 8);
      const short8 bB1 =
          *(const short8*)(bcur + ((4 + quad) * BCH + col + 16) * 8);
      const short8 bB2 =
          *(const short8*)(bcur + ((8 + quad) * BCH + col + 16) * 8);
      const short8 bB3 =
          *(const short8*)(bcur + ((12 + quad) * BCH + col + 16) * 8);

      f32x4 accA = {0.f, 0.f, 0.f, 0.f}, accB = {0.f, 0.f, 0.f, 0.f};
      // 3-term split: hi.hi + lo.hi + hi.lo ; two independent chains per tile
      accA = __builtin_amdgcn_mfma_f32_16x16x32_bf16(a0, bA0, accA, 0, 0, 0);
      accB = __builtin_amdgcn_mfma_f32_16x16x32_bf16(a0, bB0, accB, 0, 0, 0);
      accA = __builtin_amdgcn_mfma_f32_16x16x32_bf16(a1, bA1, accA, 0, 0, 0);
      accB = __builtin_amdgcn_mfma_f32_16x16x32_bf16(a1, bB1, accB, 0, 0, 0);
      accA = __builtin_amdgcn_mfma_f32_16x16x32_bf16(a2, bA0, accA, 0, 0, 0);
      accB = __builtin_amdgcn_mfma_f32_16x16x32_bf16(a2, bB0, accB, 0, 0, 0);
      accA = __builtin_amdgcn_mfma_f32_16x16x32_bf16(a3, bA1, accA, 0, 0, 0);
      accB = __builtin_amdgcn_mfma_f32_16x16x32_bf16(a3, bB1, accB, 0, 0, 0);
      accA = __builtin_amdgcn_mfma_f32_16x16x32_bf16(a0, bA2, accA, 0, 0, 0);
      accB = __builtin_amdgcn_mfma_f32_16x16x32_bf16(a0, bB2, accB, 0, 0, 0);
      accA = __builtin_amdgcn_mfma_f32_16x16x32_bf16(a1, bA3, accA, 0, 0, 0);
      accB = __builtin_amdgcn_mfma_f32_16x16x32_bf16(a1, bB3, accB, 0, 0, 0);

      // fold with exact per-lane top-2; strict < + ascending scan keeps lowest k
#pragma unroll
      for (int reg = 0; reg < 4; ++reg) {
        {
          float d = fmaf(-2.0f, accA[reg], rzv[reg] + enA);
          int k = kb + col;
          bool w1 = d < b1d[reg];
          bool w2 = d < b2d[reg];
          b2d[reg] = w1 ? b1d[reg] : (w2 ? d : b2d[reg]);
          b2k[reg] = w1 ? b1k[reg] : (w2 ? k : b2k[reg]);
          b1d[reg] = w1 ? d : b1d[reg];
          b1k[reg] = w1 ? k : b1k[reg];
        }
        {
          float d = fmaf(-2.0f, accB[reg], rzv[reg] + enB);
          int k = kb + 16 + col;
          bool w1 = d < b1d[reg];
          bool w2 = d < b2d[reg];
          b2d[reg] = w1 ? b1d[reg] : (w2 ? d : b2d[reg]);
          b2k[reg] = w1 ? b1k[reg] : (w2 ? k : b2k[reg]);
          b1d[reg] = w1 ? d : b1d[reg];
          b1k[reg] = w1 ? k : b1k[reg];
        }
      }
    }

    // commit staged regs to the other pair buffer, then barrier
    if (p + 1 < NP) {
      unsigned short* bn0 = &Bsh[(p + 1) & 1][0][0];
      unsigned short* bn1 = &Bsh[(p + 1) & 1][1][0];
      *(short8*)&bn0[cslot * 8] = st00;
      *(short8*)&bn0[(cslot + 16) * 8] = st01;
      *(short8*)&bn1[cslot * 8] = st10;
      *(short8*)&bn1[(cslot + 16) * 8] = st11;
    }
    __syncthreads();
  }

  // ---- cross-lane top-2 butterfly over the 16 col-classes (within quad group)
#pragma unroll
  for (int m = 1; m < 16; m <<= 1) {
#pragma unroll
    for (int reg = 0; reg < 4; ++reg) {
      float od1 = __shfl_xor(b1d[reg], m, 64);
      int ok1 = __shfl_xor(b1k[reg], m, 64);
      float od2 = __shfl_xor(b2d[reg], m, 64);
      int ok2 = __shfl_xor(b2k[reg], m, 64);
      bool fo = (od1 < b1d[reg]) || (od1 == b1d[reg] && ok1 < b1k[reg]);
      float w1 = fo ? od1 : b1d[reg];
      int wk1 = fo ? ok1 : b1k[reg];
      float l1 = fo ? b1d[reg] : od1;
      int lk1 = fo ? b1k[reg] : ok1;
      bool so = (od2 < b2d[reg]) || (od2 == b2d[reg] && ok2 < b2k[reg]);
      float m2 = so ? od2 : b2d[reg];
      int mk2 = so ? ok2 : b2k[reg];
      bool lw = (l1 < m2) || (l1 == m2 && lk1 < mk2);
      b1d[reg] = w1;
      b1k[reg] = wk1;
      b2d[reg] = lw ? l1 : m2;
      b2k[reg] = lw ? lk1 : mk2;
    }
  }

  // writer lanes: col<4 handles row = wav*16 + quad*4 + col (using reg=col)
  if (col < 4) {
    const int row = wav * 16 + quad * 4 + col;
    float bd1 = b1d[col], bd2 = b2d[col];
    int bk1 = b1k[col], bk2 = b2k[col];
    if (bd2 - bd1 < 1e-5f) {
      // exact fp32 recompute (R3 arithmetic) of the top-2 candidates
      const int grow = rowbase + row;
      const float4* zp = (const float4*)(z + (size_t)grow * D);
      float s0 = 0.f, s1 = 0.f, s2 = 0.f, s3 = 0.f;
#pragma unroll
      for (int i = 0; i < 16; ++i) {
        float4 v = zp[i];
        s0 = fmaf(v.x, v.x, s0);
        s1 = fmaf(v.y, v.y, s1);
        s2 = fmaf(v.z, v.z, s2);
        s3 = fmaf(v.w, v.w, s3);
      }
      const float rzx = (s0 + s1) + (s2 + s3);
      float dx[2];
      int kk[2] = {bk1, bk2};
#pragma unroll
      for (int c = 0; c < 2; ++c) {
        const float4* e4 = (const float4*)(cb + (size_t)kk[c] * D);
        float d0 = 0.f, d1 = 0.f, d2 = 0.f, d3 = 0.f;
#pragma unroll
        for (int i = 0; i < 16; ++i) {
          float4 v = e4[i];
          float4 zv = zp[i];
          d0 = fmaf(zv.x, v.x, d0);
          d1 = fmaf(zv.y, v.y, d1);
          d2 = fmaf(zv.z, v.z, d2);
          d3 = fmaf(zv.w, v.w, d3);
        }
        float dot = (d0 + d1) + (d2 + d3);
        dx[c] = (rzx + scbn[kk[c]]) - 2.0f * dot;
      }
      if ((dx[1] < dx[0]) || (dx[1] == dx[0] && bk2 < bk1)) bk1 = bk2;
    }
    skf[row] = bk1;
    out_idx[rowbase + row] = (float)bk1;
    atomicAdd(&lhist[bk1], 1u);
  }
  __syncthreads();

  // ---- flush per-block histogram: one global atomic per distinct code
#pragma unroll
  for (int j = 0; j < KC / 256; ++j) {
    unsigned int c = lhist[tid + 256 * j];
    if (c) atomicAdd(&hist[tid + 256 * j], c);
  }

  // ---- epilogue: quantized write (exact fp32 codebook rows) + loss partial
  float lsum = 0.f;
#pragma unroll
  for (int it = 0; it < 4; ++it) {
    int f4 = it * 256 + tid;
    int r = f4 >> 4;
    int c4 = (f4 & 15) * 4;
    int bk = skf[r];
    const float4 q = *(const float4*)(cb + (size_t)bk * D + c4);
    const int grow = rowbase + r;
    const float4 zv = *(const float4*)(z + (size_t)grow * D + c4);
    *(float4*)(out_q + (size_t)grow * D + c4) = q;
    float ax = q.x - zv.x, ay = q.y - zv.y, az = q.z - zv.z, aw = q.w - zv.w;
    lsum += ax * ax + ay * ay + az * az + aw * aw;
  }
#pragma unroll
  for (int off = 32; off > 0; off >>= 1) lsum += __shfl_down(lsum, off, 64);
  if (lane == 0) swav[wav] = lsum;
  __syncthreads();
  if (tid == 0) {
    atomicAdd(loss_acc, (swav[0] + swav[1]) + (swav[2] + swav[3]));
  }
}

__global__ __launch_bounds__(1024) void vq_final(
    const unsigned int* __restrict__ hist, const float* __restrict__ loss_acc,
    float* __restrict__ out_loss, float* __restrict__ out_perp, float inv_n,
    float inv_nd) {
  __shared__ float part[16];
  const int t = threadIdx.x;
  const int lane = t & 63;
  const int wav = t >> 6;
  float p = (float)hist[t] * inv_n;
  float v = p * logf(p + 1e-10f);
#pragma unroll
  for (int off = 32; off > 0; off >>= 1) v += __shfl_down(v, off, 64);
  if (lane == 0) part[wav] = v;
  __syncthreads();
  if (t == 0) {
    float s = 0.f;
#pragma unroll
    for (int j = 0; j < 16; ++j) s += part[j];
    *out_perp = expf(-s);
    // q_latent + 0.25*e_latent, both numerically mean((q-z)^2)
    *out_loss = 1.25f * loss_acc[0] * inv_nd;
  }
}

extern "C" void kernel_launch(void* const* d_in, const int* in_sizes, int n_in,
                              void* d_out, int out_size, void* d_ws,
                              size_t ws_size, hipStream_t stream) {
  (void)n_in;
  (void)out_size;
  (void)ws_size;
  const float* z = (const float*)d_in[0];
  const float* cb = (const float*)d_in[1];
  const int N = in_sizes[0] / D;  // 32768

  // Output layout (flat float32, reference return order):
  float* out_q = (float*)d_out;                     // N*D
  float* out_loss = (float*)d_out + (size_t)N * D;  // 1
  float* out_idx = out_loss + 1;                    // N
  float* out_perp = out_idx + N;                    // 1

  // Workspace (floats): hist[1024] @0, loss_acc @1024, cbn[1024] @1040,
  // bsplit (short[1024*128]) @ float-idx 2064 (byte 8256, 16B-aligned).
  unsigned int* hist = (unsigned int*)d_ws;
  float* loss_acc = (float*)d_ws + 1024;
  float* cbn = (float*)d_ws + 1040;
  unsigned short* bsplit = (unsigned short*)((float*)d_ws + 2064);

  vq_prep<<<dim3(KC / 256), dim3(256), 0, stream>>>(cb, bsplit, cbn, hist,
                                                    loss_acc);
  vq_main<<<dim3(N / ROWS), dim3(256), 0, stream>>>(z, bsplit, cbn, cb, out_q,
                                                    out_idx, hist, loss_acc);
  vq_final<<<dim3(1), dim3(1024), 0, stream>>>(
      hist, loss_acc, out_loss, out_perp, 1.0f / (float)N,
      1.0f / ((float)N * (float)D));
}